// Round 10
// baseline (415.394 us; speedup 1.0000x reference)
//
#include <hip/hip_runtime.h>
#include <stdint.h>

#define B_   32
#define L_   512
#define DT_  4
#define NT_  20
#define SMP_ 50
#define H_   132
#define HPAD 144      // padded feature rows (9 n-tiles of 16)
#define KSTR 136      // bf16 W-image k-stride (shorts), 272B = 17x16B -> ds_read_b128 aligned
#define KCH  5        // 5 k-chunks of 32 (K padded 132 -> 160)
#define NTIL 9
#define WBF_N (HPAD*KSTR)      // 19584 shorts
#define ITILE 16      // k1 i-rows per block
#define SCSTR 520     // k1 score-row stride (shorts)
#define HIDS  136     // k1 hid row stride (floats)
#define HNLS  160     // k1 fused-decoder hn LDS row stride (shorts)
#define WDROW 160     // [Win;Wpred] image rows (152 used)
#define NTIL3 10      // decoder n-tiles
#define EBLK 512      // k0 embed blocks (32 positions each)
#define EPOS 32       // positions per embed block
#define NP_  16384    // B_*L_ positions (sc4 plane stride)
#define K4T  640      // k4 threads (10 waves)
#define K4W  10       // k4 waves per block

typedef float  float4v __attribute__((ext_vector_type(4)));
typedef short  short8  __attribute__((ext_vector_type(8)));
typedef unsigned int uint4v __attribute__((ext_vector_type(4)));

#if __has_builtin(__builtin_rotateleft32)
#define ROTL(x,r) __builtin_rotateleft32((x),(r))
#elif __has_builtin(__builtin_amdgcn_alignbit)
#define ROTL(x,r) __builtin_amdgcn_alignbit((x),(x),32u-(r))
#else
#define ROTL(x,r) (((x)<<(r))|((x)>>(32u-(r))))
#endif

// ---------------- threefry2x32, key=(0,42), JAX partitionable 32-bit path ------------
// bits[f] = o0 ^ o1 of threefry2x32((0,42), ctr=(0,f))  [verified R5-R12]
__device__ __forceinline__ uint32_t tfpair(uint32_t fa, uint32_t fb){
  const uint32_t ks1 = 42u;
  const uint32_t ks2 = 0x1BD11BDAu ^ 42u;
  uint32_t a0 = 0u, b0 = 0u, a1 = fa + ks1, b1 = fb + ks1;
#define TFR(r) a0+=a1; b0+=b1; a1=ROTL(a1,(r)); b1=ROTL(b1,(r)); a1^=a0; b1^=b0;
  TFR(13) TFR(15) TFR(26) TFR(6)
  a0+=ks1; a1+=ks2+1u; b0+=ks1; b1+=ks2+1u;
  TFR(17) TFR(29) TFR(16) TFR(24)
  a0+=ks2; a1+=2u;     b0+=ks2; b1+=2u;       // ks0+2
  TFR(13) TFR(15) TFR(26) TFR(6)
  a1+=ks1+3u;          b1+=ks1+3u;            // x0+=ks0 (0)
  TFR(17) TFR(29) TFR(16) TFR(24)
  a0+=ks1; a1+=ks2+4u; b0+=ks1; b1+=ks2+4u;
  TFR(13) TFR(15) TFR(26) TFR(6)
  a0+=ks2; a1+=5u;     b0+=ks2; b1+=5u;       // ks0+5
#undef TFR
  uint32_t Ya = ((a0 ^ a1) >> 9) + 0x3f808000u;   // bf16 bits in [31:16], RHU rounding
  uint32_t Yb = ((b0 ^ b1) >> 9) + 0x3f808000u;
#if __has_builtin(__builtin_amdgcn_perm)
  return __builtin_amdgcn_perm(Ya, Yb, 0x03020706u);  // {Yb.hi16, Ya.hi16}
#else
  return (Yb & 0xffff0000u) | (Ya >> 16);
#endif
}

__device__ __forceinline__ float softplus_fast(float x){
  return fmaxf(x,0.f) + __logf(1.f + __expf(-fabsf(x)));
}

__device__ __forceinline__ short f2bf(float f){   // fp32 -> bf16 RNE
  uint32_t u = __float_as_uint(f);
  u += 0x7fffu + ((u>>16)&1u);
  return (short)(u>>16);
}

__device__ __forceinline__ float bf_round(float f){   // fp32 -> bf16 -> fp32
  uint32_t u = __float_as_uint(f);
  u += 0x7fffu + ((u>>16)&1u);
  u &= 0xffff0000u;
  return __uint_as_float(u);
}

// ---------------- K0: embeddings -> transposed bf16 hvT image (coalesced) -----------
// R21: 32-position embed tiles (531 blocks). R22: sc4 stored as 4 SoA planes
// (dg | dg2 | dl | dl2, each NP_ floats) so k1's staging reads are coalesced.
__global__ __launch_bounds__(256) void k0_embed(
    const int* __restrict__ etype, const float* __restrict__ etime,
    const float* __restrict__ Wt,  const float* __restrict__ temb,
    const float* __restrict__ Wg,  const float* __restrict__ Wl,
    const float* __restrict__ Wn,  const float* __restrict__ Win,
    const float* __restrict__ Wpred,
    uint16_t* __restrict__ hvT, float* __restrict__ sc4, float* __restrict__ outmean,
    uint16_t* __restrict__ wbf, uint16_t* __restrict__ wd, float* __restrict__ rs){
  int blk = blockIdx.x, tid = threadIdx.x;
  if (blk < EBLK){
    __shared__ __align__(16) uint16_t tile[HPAD*EPOS];   // 9216 B
    __shared__ float tvec[EPOS];
    int b = blk >> 4, l0 = (blk & 15)*EPOS;
    int base = b*L_ + l0;
    if (tid < EPOS) tvec[tid] = etime[base + tid];
    __syncthreads();
    const float M = -0.07195578414202429f;  // -ln(10000)/128
    #pragma unroll
    for (int rep = 0; rep < 8; ++rep){      // 64 k x 32 p = 2048 elems
      int idx = rep*256 + tid;
      int k = idx >> 5, p = idx & (EPOS-1);
      float dterm = __expf((float)(2*k) * M);
      float ang = (float)(l0 + p) * dterm + tvec[p] * Wt[k];
      float sv, cv;
      sincosf(ang, &sv, &cv);
      tile[k*EPOS + p]      = (uint16_t)f2bf(sv);
      tile[(64+k)*EPOS + p] = (uint16_t)f2bf(cv);
    }
    if (tid < 128){                          // type rows 128..131 x 32 p
      int r = 128 + (tid >> 5), p = tid & (EPOS-1);
      int et = etype[base + p];
      tile[r*EPOS + p] = (uint16_t)f2bf(temb[et*4 + (r-128)]);
    }
    // pad rows 132..143 zero (12 rows x 32)
    for (int e = tid; e < 12*EPOS; e += 256)
      tile[(H_ + (e >> 5))*EPOS + (e & (EPOS-1))] = 0;
    if (tid < EPOS){
      int bl = base + tid;
      int et = etype[bl];
      float t0 = temb[et*4+0], t1 = temb[et*4+1], t2 = temb[et*4+2], t3 = temb[et*4+3];
      sc4[bl]          = t0*Wg[0]+t1*Wg[1]+t2*Wg[2]+t3*Wg[3];  // dg  (j-side)
      sc4[NP_ + bl]    = t0*Wg[4]+t1*Wg[5]+t2*Wg[6]+t3*Wg[7];  // dg2 (i-side)
      sc4[2*NP_ + bl]  = t0*Wl[0]+t1*Wl[1]+t2*Wl[2]+t3*Wl[3];  // dl
      sc4[3*NP_ + bl]  = t0*Wl[4]+t1*Wl[5]+t2*Wl[6]+t3*Wl[7];  // dl2
      outmean[bl] = 0.f;                                        // zero for k4 atomics
    }
    __syncthreads();
    // writeout: 144 rows x 64B = 576 x 16B chunks
    for (int e = tid; e < HPAD*4; e += 256){
      int r = e >> 2, c = e & 3;
      ((uint4v*)(hvT + ((size_t)b*HPAD + r)*L_ + l0))[c] = ((const uint4v*)(tile + r*EPOS))[c];
    }
  } else {
    int pb = blk - EBLK;               // 0..18
    if (pb < 9){                       // W_noise bf16 image + rowsum(bf16 W)
      for (int e = tid; e < 16*KSTR; e += 256){
        int r = e / KSTR, k = e - r*KSTR;
        int n = pb*16 + r;
        uint16_t v = 0;
        if (n < H_ && k < H_) v = (uint16_t)f2bf(Wn[n*H_ + k]);
        wbf[n*KSTR + k] = v;
      }
      if (tid < 16){
        int n = pb*16 + tid;
        if (n < H_){
          float s = 0.f;
          const float* row = Wn + (size_t)n*H_;
          #pragma unroll 4
          for (int k = 0; k < H_; ++k) s += bf_round(row[k]);
          rs[n] = s;
        }
      }
    } else {                           // [Win; Wpred] bf16 image
      int rb = pb - 9;                 // 0..9
      for (int e = tid; e < 16*KSTR; e += 256){
        int r = e / KSTR, k = e - r*KSTR;
        int n = rb*16 + r;
        uint16_t v = 0;
        if (k < H_){
          if (n < H_)          v = (uint16_t)f2bf(Win[n*H_ + k]);
          else if (n < H_+NT_) v = (uint16_t)f2bf(Wpred[(n-H_)*H_ + k]);
        }
        wd[n*KSTR + k] = v;
      }
    }
  }
}

// ---------------- K1: attention flash-tile + LN + fused decoder --------------------
// R22: grid transposed (id = b + 32*i_tile) for per-CU load balance; sc4 SoA.
// R20: causal truncation (KTM4 k-tiles). Decoder writes cvec - rs.
__global__ __launch_bounds__(256) void k1_attn(
    const float* __restrict__ etime, const float* __restrict__ sc4,
    const uint16_t* __restrict__ hvT, const uint16_t* __restrict__ wd,
    const float* __restrict__ bgp, const float* __restrict__ blp,
    const float* __restrict__ gamma, const float* __restrict__ beta,
    const float* __restrict__ rs,
    float* __restrict__ cvec, float* __restrict__ outp){
  __shared__ __align__(16) uint16_t scb[ITILE*SCSTR];
  __shared__ float jt[L_], jg[L_], jl[L_];
  __shared__ float rt[ITILE], rg[ITILE], rl[ITILE];
  __shared__ __align__(16) float hid[ITILE*HIDS];
  __shared__ __align__(16) uint16_t hnl[ITILE*HNLS];
  __shared__ float logit[ITILE*NT_];
  __shared__ float mur[ITILE], rsr[ITILE];
  int b = blockIdx.x, i0 = blockIdx.y*ITILE, base = b*L_;   // R22: transposed
  int tid = threadIdx.x;
  float bg = bgp[0], blv = blp[0];
  int KTM4 = (((i0 + 14) >> 5) + 4) & ~3;   // 4..16 k-tiles actually needed (rounded to 4)
  int JMAX4 = KTM4 << 5;                    // 128..512
  for (int j = tid; j < L_; j += 256){
    jt[j] = etime[base+j];
    jg[j] = sc4[base+j];            // dg plane (SoA, coalesced)
    jl[j] = sc4[2*NP_ + base+j];    // dl plane
  }
  if (tid < ITILE){
    rt[tid] = etime[base+i0+tid];
    rg[tid] = sc4[NP_   + base+i0+tid];   // dg2
    rl[tid] = sc4[3*NP_ + base+i0+tid];   // dl2
  }
  __syncthreads();
  // phase 1: score tile, truncated at JMAX4 (j >= JMAX4 never read by MFMA)
  for (int e = tid; e < ITILE*L_; e += 256){
    int r = e >> 9, j = e & (L_-1);
    if (j >= JMAX4) continue;                 // wave-uniform skip
    float v = 0.f;
    if (j < i0 + r){
      float gate = __frcp_rn(1.f + __expf(-(jg[j] + rg[r] + bg)));
      float ls   = softplus_fast(jl[j] + rl[r] + blv) + 1e-6f;
      float d    = rt[r] - jt[j];
      float t2   = 2.f*ls*ls;
      v = gate * t2 * __frcp_rn(t2 + d*d);
    }
    scb[r*SCSTR + j] = (uint16_t)f2bf(v);
  }
  __syncthreads();
  // phase 2: hidden[16][H] = scores @ hv  (MFMA 16x16x32, B from hvT short8)
  int wave = tid>>6, lane = tid&63, q = lane>>4, col = lane&15;
  for (int nt = wave; nt < NTIL; nt += 4){
    int n = nt*16 + col;
    const uint16_t* bT = hvT + ((size_t)b*HPAD + n)*L_;   // 144 rows, pad rows zero
    float4v acc = {0.f,0.f,0.f,0.f};
    if (KTM4 == 16){
      // heavy blocks: R13 path -- all 16 independent B-loads in flight
      short8 bfr[16];
      #pragma unroll
      for (int kt = 0; kt < 16; ++kt)
        bfr[kt] = *(const short8*)&bT[kt*32 + q*8];
      #pragma unroll
      for (int kt = 0; kt < 16; ++kt){
        short8 af = *(const short8*)&scb[col*SCSTR + kt*32 + q*8];
        acc = __builtin_amdgcn_mfma_f32_16x16x32_bf16(af, bfr[kt], acc, 0, 0, 0);
      }
    } else {
      for (int ktc = 0; ktc < KTM4; ktc += 4){
        const uint16_t* bc = bT + ktc*32 + q*8;
        short8 b0 = *(const short8*)&bc[0];
        short8 b1 = *(const short8*)&bc[32];
        short8 b2 = *(const short8*)&bc[64];
        short8 b3 = *(const short8*)&bc[96];
        const uint16_t* ac = scb + col*SCSTR + ktc*32 + q*8;
        acc = __builtin_amdgcn_mfma_f32_16x16x32_bf16(*(const short8*)&ac[0],  b0, acc, 0, 0, 0);
        acc = __builtin_amdgcn_mfma_f32_16x16x32_bf16(*(const short8*)&ac[32], b1, acc, 0, 0, 0);
        acc = __builtin_amdgcn_mfma_f32_16x16x32_bf16(*(const short8*)&ac[64], b2, acc, 0, 0, 0);
        acc = __builtin_amdgcn_mfma_f32_16x16x32_bf16(*(const short8*)&ac[96], b3, acc, 0, 0, 0);
      }
    }
    if (n < H_){
      #pragma unroll
      for (int rr = 0; rr < 4; ++rr)
        hid[(q*4+rr)*HIDS + n] = acc[rr];    // C/D: row=q*4+rr, col=n
    }
  }
  __syncthreads();
  // LayerNorm stats
  #pragma unroll
  for (int rr = 0; rr < 4; ++rr){
    int r = wave*4 + rr;
    float x0 = hid[r*HIDS + lane];
    float x1 = hid[r*HIDS + 64 + lane];
    float x2 = (lane<4) ? hid[r*HIDS + 128 + lane] : 0.f;
    float s1 = x0+x1+x2, s2 = x0*x0+x1*x1+x2*x2;
    #pragma unroll
    for (int m=32; m; m>>=1){ s1 += __shfl_xor(s1, m, 64); s2 += __shfl_xor(s2, m, 64); }
    if (lane == 0){
      float mu = s1 * (1.f/132.f);
      float var = s2 * (1.f/132.f) - mu*mu;
      mur[r] = mu; rsr[r] = rsqrtf(var + 1e-6f);
    }
  }
  __syncthreads();
  if (tid < HNLS){
    if (tid < H_){
      float g = gamma[tid], be = beta[tid];
      #pragma unroll 4
      for (int r = 0; r < ITILE; ++r)
        hnl[r*HNLS + tid] = (uint16_t)f2bf((hid[r*HIDS+tid]-mur[r])*rsr[r]*g + be);
    } else {
      #pragma unroll 4
      for (int r = 0; r < ITILE; ++r) hnl[r*HNLS + tid] = 0;
    }
  }
  __syncthreads();
  // fused decoder: hn(16x132) @ wd(152x132)^T -> (cvec - rs) + logits
  short8 afr[KCH];
  #pragma unroll
  for (int kc = 0; kc < KCH; ++kc)
    afr[kc] = *(const short8*)&hnl[col*HNLS + kc*32 + q*8];   // A[m=col][k]
  for (int nt = wave; nt < NTIL3; nt += 4){
    float4v acc = {0.f,0.f,0.f,0.f};
    const short8* bp = (const short8*)&wd[(nt*16+col)*KSTR];
    #pragma unroll
    for (int kc = 0; kc < KCH; ++kc){
      // kc=4,q>0 reads past wd row end: A zero at k>=132 -- harmless
      short8 bfr = bp[kc*4 + q];
      acc = __builtin_amdgcn_mfma_f32_16x16x32_bf16(afr[kc], bfr, acc, 0, 0, 0);
    }
    int n = nt*16 + col;
    #pragma unroll
    for (int rr = 0; rr < 4; ++rr){
      int lr = q*4 + rr;
      if (n < H_)            cvec[(size_t)(base+i0+lr)*H_ + n] = acc[rr] - rs[n];
      else if (n < H_+NT_)   logit[lr*NT_ + (n-H_)] = acc[rr];
    }
  }
  __syncthreads();
  if (tid < ITILE){
    float mx = -1e30f;
    #pragma unroll
    for (int j=0;j<NT_;++j) mx = fmaxf(mx, logit[tid*NT_+j]);
    float ex[NT_]; float ssum = 0.f;
    #pragma unroll
    for (int j=0;j<NT_;++j){ ex[j] = __expf(logit[tid*NT_+j]-mx); ssum += ex[j]; }
    float inv = __frcp_rn(ssum);
    #pragma unroll
    for (int j=0;j<NT_;++j)
      outp[(size_t)(B_*L_) + (size_t)(base+i0+tid)*NT_ + j] = ex[j]*inv;
  }
}

// ---------------- K4: GAN sampler (R23: 10-wave blocks, zero idle waves) -----------
// R23: grid z 7->5, block 512->640 (10 waves): 51,200 wave-slots for 51,200
// samples (was 57,344 -> 10.7% of waves ran staging+exit with no RNG work in an
// issue-bound kernel). s = sch*10 + wave always < 50: sample guard and part[]
// zero-init removed (all 160 entries written unconditionally). Also 28% fewer
// W-image stagings (7168 -> 5120 blocks). launch_bounds(640,3): 7.5 waves/EU
// -> VGPR cap ~68 >= the ~48 this body needs (watch WRITE_SIZE for spill).
__global__ __launch_bounds__(K4T, 3) void k4_sampler(
    const uint16_t* __restrict__ wbf, const float* __restrict__ cvec,
    const float* __restrict__ wt, float* __restrict__ outmean){
  __shared__ __align__(16) short Wlds[WBF_N + 32];  // +32: slack for kc=4 tail over-read
  __shared__ float wtlds[HPAD];
  __shared__ float part[K4W*16];
  int tid = threadIdx.x, lane = tid & 63;
  int l0 = blockIdx.x*16, b = blockIdx.y, sch = blockIdx.z;
  int bl0 = b*L_ + l0;

  {   // stage W (incl. slack words -- keeps kc=4 over-read finite): 2452 x 16B
    const uint4v* g = (const uint4v*)wbf;
    uint4v* l = (uint4v*)Wlds;
    for (int idx = tid; idx < (WBF_N+32)/8; idx += K4T) l[idx] = g[idx];
  }
  if (tid < HPAD) wtlds[tid] = (tid < H_) ? wt[tid] : 0.f;
  __syncthreads();

  int wave = tid >> 6;
  int q = lane >> 4, col = lane & 15;
  int s = sch*K4W + wave;                 // 0..49, always valid
  {
    uint32_t fbase = (uint32_t)(bl0 + col)*(uint32_t)(SMP_*H_)
                   + (uint32_t)s*(uint32_t)H_;
    uint32_t fbq = fbase + (uint32_t)(q*8);
    uint4v afu[KCH];
    #pragma unroll
    for (int kc = 0; kc < 4; ++kc){
      #pragma unroll
      for (int t = 0; t < 4; ++t)
        afu[kc][t] = tfpair(fbq + (uint32_t)(kc*32 + 2*t),
                            fbq + (uint32_t)(kc*32 + 2*t + 1));
    }
    {   // tail features 128..131: one full-wave stream (q even:128/129, q odd:130/131)
      uint32_t ft = fbase + 128u + (uint32_t)((q & 1)*2);
      uint32_t w  = tfpair(ft, ft + 1u);
      uint32_t wo = (uint32_t)__shfl_xor((int)w, 16, 64);
      uint4v a4 = {0u,0u,0u,0u};
      if (q == 0){ a4[0] = w; a4[1] = wo; }
      afu[4] = a4;
    }
    const float* cbase = cvec + (size_t)(bl0 + q*4)*H_;
    float racc0=0.f, racc1=0.f, racc2=0.f, racc3=0.f;
    for (int nt = 0; nt < NTIL; ++nt){
      float4v acc = {0.f,0.f,0.f,0.f};
      const short8* bp = (const short8*)&Wlds[(nt*16+col)*KSTR];
      #pragma unroll
      for (int kc = 0; kc < KCH; ++kc){
        short8 bfr = bp[kc*4 + q];
        acc = __builtin_amdgcn_mfma_f32_16x16x32_bf16(
                 __builtin_bit_cast(short8, afu[kc]), bfr, acc, 0, 0, 0);
      }
      int n = nt*16 + col;
      float wv = wtlds[n];
      const float* cb = cbase + n;
      racc0 += fmaxf(acc[0] + cb[0*H_], 0.f)*wv;
      racc1 += fmaxf(acc[1] + cb[1*H_], 0.f)*wv;
      racc2 += fmaxf(acc[2] + cb[2*H_], 0.f)*wv;
      racc3 += fmaxf(acc[3] + cb[3*H_], 0.f)*wv;
    }
    #pragma unroll
    for (int m = 1; m < 16; m <<= 1){
      racc0 += __shfl_xor(racc0, m, 64);
      racc1 += __shfl_xor(racc1, m, 64);
      racc2 += __shfl_xor(racc2, m, 64);
      racc3 += __shfl_xor(racc3, m, 64);
    }
    if (col == 0){
      part[wave*16 + q*4 + 0] = 0.02f * softplus_fast(racc0);
      part[wave*16 + q*4 + 1] = 0.02f * softplus_fast(racc1);
      part[wave*16 + q*4 + 2] = 0.02f * softplus_fast(racc2);
      part[wave*16 + q*4 + 3] = 0.02f * softplus_fast(racc3);
    }
  }
  __syncthreads();
  if (tid < 16){
    float v = 0.f;
    #pragma unroll
    for (int w = 0; w < K4W; ++w) v += part[w*16 + tid];
    atomicAdd(&outmean[bl0 + tid], v);
  }
}

// ---------------- launch ----------------
extern "C" void kernel_launch(void* const* d_in, const int* in_sizes, int n_in,
                              void* d_out, int out_size, void* d_ws, size_t ws_size,
                              hipStream_t stream){
  const int*   etype = (const int*)  d_in[0];
  const float* etime = (const float*)d_in[1];
  const float* Wt    = (const float*)d_in[3];
  const float* temb  = (const float*)d_in[4];
  const float* Wg    = (const float*)d_in[5];
  const float* bgp   = (const float*)d_in[6];
  const float* Wl    = (const float*)d_in[7];
  const float* blp   = (const float*)d_in[8];
  const float* gamma = (const float*)d_in[9];
  const float* beta  = (const float*)d_in[10];
  const float* Win   = (const float*)d_in[11];
  const float* Wn    = (const float*)d_in[12];
  const float* wtm   = (const float*)d_in[13];
  const float* Wpred = (const float*)d_in[14];
  float* out = (float*)d_out;

  uint16_t* hvT   = (uint16_t*)d_ws;                        // 32*144*512 shorts
  float*    sc4   = (float*)(hvT + (size_t)B_*HPAD*L_);     // 4 SoA planes x NP_ floats
  float*    cvec  = sc4 + (size_t)NP_*4;                    // 16384*132 floats
  float*    rs    = cvec + (size_t)NP_*H_;                  // 132 (+pad to 256)
  uint16_t* wbf   = (uint16_t*)(rs + 256);                  // WBF_N shorts
  uint16_t* wd    = wbf + (size_t)WBF_N;                    // WDROW*KSTR shorts

  k0_embed  <<<dim3(EBLK+19),  dim3(256), 0, stream>>>(etype, etime, Wt, temb, Wg, Wl,
                                                       Wn, Win, Wpred, hvT, sc4, out, wbf, wd, rs);
  k1_attn   <<<dim3(32,32),    dim3(256), 0, stream>>>(etime, sc4, hvT, wd, bgp, blp,
                                                       gamma, beta, rs, cvec, out);
  k4_sampler<<<dim3(32,32,5),  dim3(K4T), 0, stream>>>(wbf, cvec, wtm, out);
}

// Round 11
// 358.462 us; speedup vs baseline: 1.1588x; 1.1588x over previous
//
#include <hip/hip_runtime.h>
#include <stdint.h>

#define B_   32
#define L_   512
#define DT_  4
#define NT_  20
#define SMP_ 50
#define H_   132
#define HPAD 144      // padded feature rows (9 n-tiles of 16)
#define KSTR 136      // bf16 W-image k-stride (shorts), 272B = 17x16B -> ds_read_b128 aligned
#define KCH  5        // 5 k-chunks of 32 (K padded 132 -> 160)
#define NTIL 9
#define WBF_N (HPAD*KSTR)      // 19584 shorts
#define ITILE 16      // k1 i-rows per block
#define SCSTR 520     // k1 score-row stride (shorts)
#define HIDS  136     // k1 hid row stride (floats)
#define HNLS  160     // k1 fused-decoder hn LDS row stride (shorts)
#define WDROW 160     // [Win;Wpred] image rows (152 used)
#define NTIL3 10      // decoder n-tiles
#define EBLK 512      // k0 embed blocks (32 positions each)
#define EPOS 32       // positions per embed block
#define NP_  16384    // B_*L_ positions (sc4 plane stride)

typedef float  float4v __attribute__((ext_vector_type(4)));
typedef short  short8  __attribute__((ext_vector_type(8)));
typedef unsigned int uint4v __attribute__((ext_vector_type(4)));

#if __has_builtin(__builtin_rotateleft32)
#define ROTL(x,r) __builtin_rotateleft32((x),(r))
#elif __has_builtin(__builtin_amdgcn_alignbit)
#define ROTL(x,r) __builtin_amdgcn_alignbit((x),(x),32u-(r))
#else
#define ROTL(x,r) (((x)<<(r))|((x)>>(32u-(r))))
#endif

// ---------------- threefry2x32, key=(0,42), JAX partitionable 32-bit path ------------
// bits[f] = o0 ^ o1 of threefry2x32((0,42), ctr=(0,f))  [verified R5-R12]
__device__ __forceinline__ uint32_t tfpair(uint32_t fa, uint32_t fb){
  const uint32_t ks1 = 42u;
  const uint32_t ks2 = 0x1BD11BDAu ^ 42u;
  uint32_t a0 = 0u, b0 = 0u, a1 = fa + ks1, b1 = fb + ks1;
#define TFR(r) a0+=a1; b0+=b1; a1=ROTL(a1,(r)); b1=ROTL(b1,(r)); a1^=a0; b1^=b0;
  TFR(13) TFR(15) TFR(26) TFR(6)
  a0+=ks1; a1+=ks2+1u; b0+=ks1; b1+=ks2+1u;
  TFR(17) TFR(29) TFR(16) TFR(24)
  a0+=ks2; a1+=2u;     b0+=ks2; b1+=2u;       // ks0+2
  TFR(13) TFR(15) TFR(26) TFR(6)
  a1+=ks1+3u;          b1+=ks1+3u;            // x0+=ks0 (0)
  TFR(17) TFR(29) TFR(16) TFR(24)
  a0+=ks1; a1+=ks2+4u; b0+=ks1; b1+=ks2+4u;
  TFR(13) TFR(15) TFR(26) TFR(6)
  a0+=ks2; a1+=5u;     b0+=ks2; b1+=5u;       // ks0+5
#undef TFR
  uint32_t Ya = ((a0 ^ a1) >> 9) + 0x3f808000u;   // bf16 bits in [31:16], RHU rounding
  uint32_t Yb = ((b0 ^ b1) >> 9) + 0x3f808000u;
#if __has_builtin(__builtin_amdgcn_perm)
  return __builtin_amdgcn_perm(Ya, Yb, 0x03020706u);  // {Yb.hi16, Ya.hi16}
#else
  return (Yb & 0xffff0000u) | (Ya >> 16);
#endif
}

__device__ __forceinline__ float softplus_fast(float x){
  return fmaxf(x,0.f) + __logf(1.f + __expf(-fabsf(x)));
}

__device__ __forceinline__ short f2bf(float f){   // fp32 -> bf16 RNE
  uint32_t u = __float_as_uint(f);
  u += 0x7fffu + ((u>>16)&1u);
  return (short)(u>>16);
}

__device__ __forceinline__ float bf_round(float f){   // fp32 -> bf16 -> fp32
  uint32_t u = __float_as_uint(f);
  u += 0x7fffu + ((u>>16)&1u);
  u &= 0xffff0000u;
  return __uint_as_float(u);
}

// ---------------- K0: embeddings -> transposed bf16 hvT image (coalesced) -----------
// R21: 32-position embed tiles (531 blocks). R22: sc4 stored as 4 SoA planes.
__global__ __launch_bounds__(256) void k0_embed(
    const int* __restrict__ etype, const float* __restrict__ etime,
    const float* __restrict__ Wt,  const float* __restrict__ temb,
    const float* __restrict__ Wg,  const float* __restrict__ Wl,
    const float* __restrict__ Wn,  const float* __restrict__ Win,
    const float* __restrict__ Wpred,
    uint16_t* __restrict__ hvT, float* __restrict__ sc4, float* __restrict__ outmean,
    uint16_t* __restrict__ wbf, uint16_t* __restrict__ wd, float* __restrict__ rs){
  int blk = blockIdx.x, tid = threadIdx.x;
  if (blk < EBLK){
    __shared__ __align__(16) uint16_t tile[HPAD*EPOS];   // 9216 B
    __shared__ float tvec[EPOS];
    int b = blk >> 4, l0 = (blk & 15)*EPOS;
    int base = b*L_ + l0;
    if (tid < EPOS) tvec[tid] = etime[base + tid];
    __syncthreads();
    const float M = -0.07195578414202429f;  // -ln(10000)/128
    #pragma unroll
    for (int rep = 0; rep < 8; ++rep){      // 64 k x 32 p = 2048 elems
      int idx = rep*256 + tid;
      int k = idx >> 5, p = idx & (EPOS-1);
      float dterm = __expf((float)(2*k) * M);
      float ang = (float)(l0 + p) * dterm + tvec[p] * Wt[k];
      float sv, cv;
      sincosf(ang, &sv, &cv);
      tile[k*EPOS + p]      = (uint16_t)f2bf(sv);
      tile[(64+k)*EPOS + p] = (uint16_t)f2bf(cv);
    }
    if (tid < 128){                          // type rows 128..131 x 32 p
      int r = 128 + (tid >> 5), p = tid & (EPOS-1);
      int et = etype[base + p];
      tile[r*EPOS + p] = (uint16_t)f2bf(temb[et*4 + (r-128)]);
    }
    // pad rows 132..143 zero (12 rows x 32)
    for (int e = tid; e < 12*EPOS; e += 256)
      tile[(H_ + (e >> 5))*EPOS + (e & (EPOS-1))] = 0;
    if (tid < EPOS){
      int bl = base + tid;
      int et = etype[bl];
      float t0 = temb[et*4+0], t1 = temb[et*4+1], t2 = temb[et*4+2], t3 = temb[et*4+3];
      sc4[bl]          = t0*Wg[0]+t1*Wg[1]+t2*Wg[2]+t3*Wg[3];  // dg  (j-side)
      sc4[NP_ + bl]    = t0*Wg[4]+t1*Wg[5]+t2*Wg[6]+t3*Wg[7];  // dg2 (i-side)
      sc4[2*NP_ + bl]  = t0*Wl[0]+t1*Wl[1]+t2*Wl[2]+t3*Wl[3];  // dl
      sc4[3*NP_ + bl]  = t0*Wl[4]+t1*Wl[5]+t2*Wl[6]+t3*Wl[7];  // dl2
      outmean[bl] = 0.f;                                        // zero for k4 atomics
    }
    __syncthreads();
    // writeout: 144 rows x 64B = 576 x 16B chunks
    for (int e = tid; e < HPAD*4; e += 256){
      int r = e >> 2, c = e & 3;
      ((uint4v*)(hvT + ((size_t)b*HPAD + r)*L_ + l0))[c] = ((const uint4v*)(tile + r*EPOS))[c];
    }
  } else {
    int pb = blk - EBLK;               // 0..18
    if (pb < 9){                       // W_noise bf16 image + rowsum(bf16 W)
      for (int e = tid; e < 16*KSTR; e += 256){
        int r = e / KSTR, k = e - r*KSTR;
        int n = pb*16 + r;
        uint16_t v = 0;
        if (n < H_ && k < H_) v = (uint16_t)f2bf(Wn[n*H_ + k]);
        wbf[n*KSTR + k] = v;
      }
      if (tid < 16){
        int n = pb*16 + tid;
        if (n < H_){
          float s = 0.f;
          const float* row = Wn + (size_t)n*H_;
          #pragma unroll 4
          for (int k = 0; k < H_; ++k) s += bf_round(row[k]);
          rs[n] = s;
        }
      }
    } else {                           // [Win; Wpred] bf16 image
      int rb = pb - 9;                 // 0..9
      for (int e = tid; e < 16*KSTR; e += 256){
        int r = e / KSTR, k = e - r*KSTR;
        int n = rb*16 + r;
        uint16_t v = 0;
        if (k < H_){
          if (n < H_)          v = (uint16_t)f2bf(Win[n*H_ + k]);
          else if (n < H_+NT_) v = (uint16_t)f2bf(Wpred[(n-H_)*H_ + k]);
        }
        wd[n*KSTR + k] = v;
      }
    }
  }
}

// ---------------- K1: attention flash-tile + LN + fused decoder (512 threads) ------
// R24: 256 -> 512 threads (8 waves). Halves every per-block serial phase: score
// 32->16 iters/thread, MFMA max 3->2 tiles/wave, decoder 3->2, LN 4->2 rows.
// 8-wave indexing identical to the R1-R3 fused kernel's phase A (test-proven).
// R22: transposed grid + SoA sc4. R20: causal truncation; decoder writes cvec-rs.
__global__ __launch_bounds__(512) void k1_attn(
    const float* __restrict__ etime, const float* __restrict__ sc4,
    const uint16_t* __restrict__ hvT, const uint16_t* __restrict__ wd,
    const float* __restrict__ bgp, const float* __restrict__ blp,
    const float* __restrict__ gamma, const float* __restrict__ beta,
    const float* __restrict__ rs,
    float* __restrict__ cvec, float* __restrict__ outp){
  __shared__ __align__(16) uint16_t scb[ITILE*SCSTR];
  __shared__ float jt[L_], jg[L_], jl[L_];
  __shared__ float rt[ITILE], rg[ITILE], rl[ITILE];
  __shared__ __align__(16) float hid[ITILE*HIDS];
  __shared__ __align__(16) uint16_t hnl[ITILE*HNLS];
  __shared__ float logit[ITILE*NT_];
  __shared__ float mur[ITILE], rsr[ITILE];
  int b = blockIdx.x, i0 = blockIdx.y*ITILE, base = b*L_;   // transposed grid
  int tid = threadIdx.x;
  float bg = bgp[0], blv = blp[0];
  int KTM4 = (((i0 + 14) >> 5) + 4) & ~3;   // 4..16 k-tiles actually needed
  int JMAX4 = KTM4 << 5;                    // 128..512
  for (int j = tid; j < L_; j += 512){
    jt[j] = etime[base+j];
    jg[j] = sc4[base+j];            // dg plane (SoA, coalesced)
    jl[j] = sc4[2*NP_ + base+j];    // dl plane
  }
  if (tid < ITILE){
    rt[tid] = etime[base+i0+tid];
    rg[tid] = sc4[NP_   + base+i0+tid];   // dg2
    rl[tid] = sc4[3*NP_ + base+i0+tid];   // dl2
  }
  __syncthreads();
  // phase 1: score tile, truncated at JMAX4
  for (int e = tid; e < ITILE*L_; e += 512){
    int r = e >> 9, j = e & (L_-1);
    if (j >= JMAX4) continue;                 // wave-uniform skip
    float v = 0.f;
    if (j < i0 + r){
      float gate = __frcp_rn(1.f + __expf(-(jg[j] + rg[r] + bg)));
      float ls   = softplus_fast(jl[j] + rl[r] + blv) + 1e-6f;
      float d    = rt[r] - jt[j];
      float t2   = 2.f*ls*ls;
      v = gate * t2 * __frcp_rn(t2 + d*d);
    }
    scb[r*SCSTR + j] = (uint16_t)f2bf(v);
  }
  __syncthreads();
  // phase 2: hidden[16][H] = scores @ hv (8 waves, nt stride 8)
  int wave = tid>>6, lane = tid&63, q = lane>>4, col = lane&15;
  for (int nt = wave; nt < NTIL; nt += 8){
    int n = nt*16 + col;
    const uint16_t* bT = hvT + ((size_t)b*HPAD + n)*L_;   // 144 rows, pad rows zero
    float4v acc = {0.f,0.f,0.f,0.f};
    if (KTM4 == 16){
      // heavy blocks: R13 path -- all 16 independent B-loads in flight
      short8 bfr[16];
      #pragma unroll
      for (int kt = 0; kt < 16; ++kt)
        bfr[kt] = *(const short8*)&bT[kt*32 + q*8];
      #pragma unroll
      for (int kt = 0; kt < 16; ++kt){
        short8 af = *(const short8*)&scb[col*SCSTR + kt*32 + q*8];
        acc = __builtin_amdgcn_mfma_f32_16x16x32_bf16(af, bfr[kt], acc, 0, 0, 0);
      }
    } else {
      for (int ktc = 0; ktc < KTM4; ktc += 4){
        const uint16_t* bc = bT + ktc*32 + q*8;
        short8 b0 = *(const short8*)&bc[0];
        short8 b1 = *(const short8*)&bc[32];
        short8 b2 = *(const short8*)&bc[64];
        short8 b3 = *(const short8*)&bc[96];
        const uint16_t* ac = scb + col*SCSTR + ktc*32 + q*8;
        acc = __builtin_amdgcn_mfma_f32_16x16x32_bf16(*(const short8*)&ac[0],  b0, acc, 0, 0, 0);
        acc = __builtin_amdgcn_mfma_f32_16x16x32_bf16(*(const short8*)&ac[32], b1, acc, 0, 0, 0);
        acc = __builtin_amdgcn_mfma_f32_16x16x32_bf16(*(const short8*)&ac[64], b2, acc, 0, 0, 0);
        acc = __builtin_amdgcn_mfma_f32_16x16x32_bf16(*(const short8*)&ac[96], b3, acc, 0, 0, 0);
      }
    }
    if (n < H_){
      #pragma unroll
      for (int rr = 0; rr < 4; ++rr)
        hid[(q*4+rr)*HIDS + n] = acc[rr];    // C/D: row=q*4+rr, col=n
    }
  }
  __syncthreads();
  // LayerNorm stats (8 waves x 2 rows)
  #pragma unroll
  for (int rr = 0; rr < 2; ++rr){
    int r = wave*2 + rr;
    float x0 = hid[r*HIDS + lane];
    float x1 = hid[r*HIDS + 64 + lane];
    float x2 = (lane<4) ? hid[r*HIDS + 128 + lane] : 0.f;
    float s1 = x0+x1+x2, s2 = x0*x0+x1*x1+x2*x2;
    #pragma unroll
    for (int m=32; m; m>>=1){ s1 += __shfl_xor(s1, m, 64); s2 += __shfl_xor(s2, m, 64); }
    if (lane == 0){
      float mu = s1 * (1.f/132.f);
      float var = s2 * (1.f/132.f) - mu*mu;
      mur[r] = mu; rsr[r] = rsqrtf(var + 1e-6f);
    }
  }
  __syncthreads();
  if (tid < HNLS){
    if (tid < H_){
      float g = gamma[tid], be = beta[tid];
      #pragma unroll 4
      for (int r = 0; r < ITILE; ++r)
        hnl[r*HNLS + tid] = (uint16_t)f2bf((hid[r*HIDS+tid]-mur[r])*rsr[r]*g + be);
    } else {
      #pragma unroll 4
      for (int r = 0; r < ITILE; ++r) hnl[r*HNLS + tid] = 0;
    }
  }
  __syncthreads();
  // fused decoder: hn(16x132) @ wd(152x132)^T -> (cvec - rs) + logits (nt stride 8)
  short8 afr[KCH];
  #pragma unroll
  for (int kc = 0; kc < KCH; ++kc)
    afr[kc] = *(const short8*)&hnl[col*HNLS + kc*32 + q*8];   // A[m=col][k]
  for (int nt = wave; nt < NTIL3; nt += 8){
    float4v acc = {0.f,0.f,0.f,0.f};
    const short8* bp = (const short8*)&wd[(nt*16+col)*KSTR];
    #pragma unroll
    for (int kc = 0; kc < KCH; ++kc){
      // kc=4,q>0 reads past wd row end: A zero at k>=132 -- harmless
      short8 bfr = bp[kc*4 + q];
      acc = __builtin_amdgcn_mfma_f32_16x16x32_bf16(afr[kc], bfr, acc, 0, 0, 0);
    }
    int n = nt*16 + col;
    #pragma unroll
    for (int rr = 0; rr < 4; ++rr){
      int lr = q*4 + rr;
      if (n < H_)            cvec[(size_t)(base+i0+lr)*H_ + n] = acc[rr] - rs[n];
      else if (n < H_+NT_)   logit[lr*NT_ + (n-H_)] = acc[rr];
    }
  }
  __syncthreads();
  if (tid < ITILE){
    float mx = -1e30f;
    #pragma unroll
    for (int j=0;j<NT_;++j) mx = fmaxf(mx, logit[tid*NT_+j]);
    float ex[NT_]; float ssum = 0.f;
    #pragma unroll
    for (int j=0;j<NT_;++j){ ex[j] = __expf(logit[tid*NT_+j]-mx); ssum += ex[j]; }
    float inv = __frcp_rn(ssum);
    #pragma unroll
    for (int j=0;j<NT_;++j)
      outp[(size_t)(B_*L_) + (size_t)(base+i0+tid)*NT_ + j] = ex[j]*inv;
  }
}

// ---------------- K4: GAN sampler (R9-proven config, byte-identical) ---------------
// R24: revert R10's 640-thread experiment (29.5% occ, 325us). This exact config
// measured 265us / 85.4% VALUBusy / 45% occ in R9.
__global__ __launch_bounds__(512, 4) void k4_sampler(
    const uint16_t* __restrict__ wbf, const float* __restrict__ cvec,
    const float* __restrict__ wt, float* __restrict__ outmean){
  __shared__ __align__(16) short Wlds[WBF_N + 32];  // +32: slack for kc=4 tail over-read
  __shared__ float wtlds[HPAD];
  __shared__ float part[128];
  int tid = threadIdx.x, lane = tid & 63;
  int l0 = blockIdx.x*16, b = blockIdx.y, sch = blockIdx.z;
  int bl0 = b*L_ + l0;

  {   // stage W (incl. slack words -- keeps kc=4 over-read finite): 2452 x 16B
    const uint4v* g = (const uint4v*)wbf;
    uint4v* l = (uint4v*)Wlds;
    for (int idx = tid; idx < (WBF_N+32)/8; idx += 512) l[idx] = g[idx];
  }
  if (tid < HPAD) wtlds[tid] = (tid < H_) ? wt[tid] : 0.f;
  if (tid < 128) part[tid] = 0.f;
  __syncthreads();

  int wave = tid >> 6;
  int q = lane >> 4, col = lane & 15;
  int s = sch*8 + wave;
  if (s < SMP_){
    uint32_t fbase = (uint32_t)(bl0 + col)*(uint32_t)(SMP_*H_)
                   + (uint32_t)s*(uint32_t)H_;
    uint32_t fbq = fbase + (uint32_t)(q*8);
    uint4v afu[KCH];
    #pragma unroll
    for (int kc = 0; kc < 4; ++kc){
      #pragma unroll
      for (int t = 0; t < 4; ++t)
        afu[kc][t] = tfpair(fbq + (uint32_t)(kc*32 + 2*t),
                            fbq + (uint32_t)(kc*32 + 2*t + 1));
    }
    {   // tail features 128..131: one full-wave stream (q even:128/129, q odd:130/131)
      uint32_t ft = fbase + 128u + (uint32_t)((q & 1)*2);
      uint32_t w  = tfpair(ft, ft + 1u);
      uint32_t wo = (uint32_t)__shfl_xor((int)w, 16, 64);
      uint4v a4 = {0u,0u,0u,0u};
      if (q == 0){ a4[0] = w; a4[1] = wo; }
      afu[4] = a4;
    }
    const float* cbase = cvec + (size_t)(bl0 + q*4)*H_;
    float racc0=0.f, racc1=0.f, racc2=0.f, racc3=0.f;
    for (int nt = 0; nt < NTIL; ++nt){
      float4v acc = {0.f,0.f,0.f,0.f};
      const short8* bp = (const short8*)&Wlds[(nt*16+col)*KSTR];
      #pragma unroll
      for (int kc = 0; kc < KCH; ++kc){
        short8 bfr = bp[kc*4 + q];
        acc = __builtin_amdgcn_mfma_f32_16x16x32_bf16(
                 __builtin_bit_cast(short8, afu[kc]), bfr, acc, 0, 0, 0);
      }
      int n = nt*16 + col;
      float wv = wtlds[n];
      const float* cb = cbase + n;
      racc0 += fmaxf(acc[0] + cb[0*H_], 0.f)*wv;
      racc1 += fmaxf(acc[1] + cb[1*H_], 0.f)*wv;
      racc2 += fmaxf(acc[2] + cb[2*H_], 0.f)*wv;
      racc3 += fmaxf(acc[3] + cb[3*H_], 0.f)*wv;
    }
    #pragma unroll
    for (int m = 1; m < 16; m <<= 1){
      racc0 += __shfl_xor(racc0, m, 64);
      racc1 += __shfl_xor(racc1, m, 64);
      racc2 += __shfl_xor(racc2, m, 64);
      racc3 += __shfl_xor(racc3, m, 64);
    }
    if (col == 0){
      part[wave*16 + q*4 + 0] = 0.02f * softplus_fast(racc0);
      part[wave*16 + q*4 + 1] = 0.02f * softplus_fast(racc1);
      part[wave*16 + q*4 + 2] = 0.02f * softplus_fast(racc2);
      part[wave*16 + q*4 + 3] = 0.02f * softplus_fast(racc3);
    }
  }
  __syncthreads();
  if (tid < 16){
    float v = 0.f;
    #pragma unroll
    for (int w = 0; w < 8; ++w) v += part[w*16 + tid];
    atomicAdd(&outmean[bl0 + tid], v);
  }
}

// ---------------- launch ----------------
extern "C" void kernel_launch(void* const* d_in, const int* in_sizes, int n_in,
                              void* d_out, int out_size, void* d_ws, size_t ws_size,
                              hipStream_t stream){
  const int*   etype = (const int*)  d_in[0];
  const float* etime = (const float*)d_in[1];
  const float* Wt    = (const float*)d_in[3];
  const float* temb  = (const float*)d_in[4];
  const float* Wg    = (const float*)d_in[5];
  const float* bgp   = (const float*)d_in[6];
  const float* Wl    = (const float*)d_in[7];
  const float* blp   = (const float*)d_in[8];
  const float* gamma = (const float*)d_in[9];
  const float* beta  = (const float*)d_in[10];
  const float* Win   = (const float*)d_in[11];
  const float* Wn    = (const float*)d_in[12];
  const float* wtm   = (const float*)d_in[13];
  const float* Wpred = (const float*)d_in[14];
  float* out = (float*)d_out;

  uint16_t* hvT   = (uint16_t*)d_ws;                        // 32*144*512 shorts
  float*    sc4   = (float*)(hvT + (size_t)B_*HPAD*L_);     // 4 SoA planes x NP_ floats
  float*    cvec  = sc4 + (size_t)NP_*4;                    // 16384*132 floats
  float*    rs    = cvec + (size_t)NP_*H_;                  // 132 (+pad to 256)
  uint16_t* wbf   = (uint16_t*)(rs + 256);                  // WBF_N shorts
  uint16_t* wd    = wbf + (size_t)WBF_N;                    // WDROW*KSTR shorts

  k0_embed  <<<dim3(EBLK+19),  dim3(256), 0, stream>>>(etype, etime, Wt, temb, Wg, Wl,
                                                       Wn, Win, Wpred, hvT, sc4, out, wbf, wd, rs);
  k1_attn   <<<dim3(32,32),    dim3(512), 0, stream>>>(etime, sc4, hvT, wd, bgp, blp,
                                                       gamma, beta, rs, cvec, out);
  k4_sampler<<<dim3(32,32,7),  dim3(512), 0, stream>>>(wbf, cvec, wtm, out);
}

// Round 12
// 350.552 us; speedup vs baseline: 1.1850x; 1.0226x over previous
//
#include <hip/hip_runtime.h>
#include <stdint.h>

#define B_   32
#define L_   512
#define DT_  4
#define NT_  20
#define SMP_ 50
#define H_   132
#define HPAD 144      // padded feature rows (9 n-tiles of 16)
#define KSTR 136      // bf16 W-image k-stride (shorts), 272B = 17x16B -> ds_read_b128 aligned
#define KCH  5        // 5 k-chunks of 32 (K padded 132 -> 160)
#define NTIL 9
#define WBF_N (HPAD*KSTR)      // 19584 shorts
#define ITILE 16      // k1 i-rows per block
#define SCSTR 520     // k1 score-row stride (shorts)
#define HIDS  136     // k1 hid row stride (floats)
#define HNLS  160     // k1 fused-decoder hn LDS row stride (shorts)
#define WDROW 160     // [Win;Wpred] image rows (152 used)
#define NTIL3 10      // decoder n-tiles
#define EBLK 512      // k0 embed blocks (32 positions each)
#define EPOS 32       // positions per embed block
#define NP_  16384    // B_*L_ positions (sc4 plane stride)

typedef float  float4v __attribute__((ext_vector_type(4)));
typedef short  short8  __attribute__((ext_vector_type(8)));
typedef unsigned int uint4v __attribute__((ext_vector_type(4)));

#if __has_builtin(__builtin_rotateleft32)
#define ROTL(x,r) __builtin_rotateleft32((x),(r))
#elif __has_builtin(__builtin_amdgcn_alignbit)
#define ROTL(x,r) __builtin_amdgcn_alignbit((x),(x),32u-(r))
#else
#define ROTL(x,r) (((x)<<(r))|((x)>>(32u-(r))))
#endif

// ---------------- threefry2x32, key=(0,42), JAX partitionable 32-bit path ------------
// bits[f] = o0 ^ o1 of threefry2x32((0,42), ctr=(0,f))  [verified R5-R12]
__device__ __forceinline__ uint32_t tfpair(uint32_t fa, uint32_t fb){
  const uint32_t ks1 = 42u;
  const uint32_t ks2 = 0x1BD11BDAu ^ 42u;
  uint32_t a0 = 0u, b0 = 0u, a1 = fa + ks1, b1 = fb + ks1;
#define TFR(r) a0+=a1; b0+=b1; a1=ROTL(a1,(r)); b1=ROTL(b1,(r)); a1^=a0; b1^=b0;
  TFR(13) TFR(15) TFR(26) TFR(6)
  a0+=ks1; a1+=ks2+1u; b0+=ks1; b1+=ks2+1u;
  TFR(17) TFR(29) TFR(16) TFR(24)
  a0+=ks2; a1+=2u;     b0+=ks2; b1+=2u;       // ks0+2
  TFR(13) TFR(15) TFR(26) TFR(6)
  a1+=ks1+3u;          b1+=ks1+3u;            // x0+=ks0 (0)
  TFR(17) TFR(29) TFR(16) TFR(24)
  a0+=ks1; a1+=ks2+4u; b0+=ks1; b1+=ks2+4u;
  TFR(13) TFR(15) TFR(26) TFR(6)
  a0+=ks2; a1+=5u;     b0+=ks2; b1+=5u;       // ks0+5
#undef TFR
  uint32_t Ya = ((a0 ^ a1) >> 9) + 0x3f808000u;   // bf16 bits in [31:16], RHU rounding
  uint32_t Yb = ((b0 ^ b1) >> 9) + 0x3f808000u;
#if __has_builtin(__builtin_amdgcn_perm)
  return __builtin_amdgcn_perm(Ya, Yb, 0x03020706u);  // {Yb.hi16, Ya.hi16}
#else
  return (Yb & 0xffff0000u) | (Ya >> 16);
#endif
}

__device__ __forceinline__ float softplus_fast(float x){
  return fmaxf(x,0.f) + __logf(1.f + __expf(-fabsf(x)));
}

__device__ __forceinline__ short f2bf(float f){   // fp32 -> bf16 RNE
  uint32_t u = __float_as_uint(f);
  u += 0x7fffu + ((u>>16)&1u);
  return (short)(u>>16);
}

__device__ __forceinline__ float bf_round(float f){   // fp32 -> bf16 -> fp32
  uint32_t u = __float_as_uint(f);
  u += 0x7fffu + ((u>>16)&1u);
  u &= 0xffff0000u;
  return __uint_as_float(u);
}

// ---------------- K0: embeddings -> transposed bf16 hvT image (coalesced) -----------
// R21: 32-position embed tiles (531 blocks). R22: sc4 stored as 4 SoA planes
// (dg | dg2 | dl | dl2, each NP_ floats) so k1's staging reads are coalesced.
__global__ __launch_bounds__(256) void k0_embed(
    const int* __restrict__ etype, const float* __restrict__ etime,
    const float* __restrict__ Wt,  const float* __restrict__ temb,
    const float* __restrict__ Wg,  const float* __restrict__ Wl,
    const float* __restrict__ Wn,  const float* __restrict__ Win,
    const float* __restrict__ Wpred,
    uint16_t* __restrict__ hvT, float* __restrict__ sc4, float* __restrict__ outmean,
    uint16_t* __restrict__ wbf, uint16_t* __restrict__ wd, float* __restrict__ rs){
  int blk = blockIdx.x, tid = threadIdx.x;
  if (blk < EBLK){
    __shared__ __align__(16) uint16_t tile[HPAD*EPOS];   // 9216 B
    __shared__ float tvec[EPOS];
    int b = blk >> 4, l0 = (blk & 15)*EPOS;
    int base = b*L_ + l0;
    if (tid < EPOS) tvec[tid] = etime[base + tid];
    __syncthreads();
    const float M = -0.07195578414202429f;  // -ln(10000)/128
    #pragma unroll
    for (int rep = 0; rep < 8; ++rep){      // 64 k x 32 p = 2048 elems
      int idx = rep*256 + tid;
      int k = idx >> 5, p = idx & (EPOS-1);
      float dterm = __expf((float)(2*k) * M);
      float ang = (float)(l0 + p) * dterm + tvec[p] * Wt[k];
      float sv, cv;
      sincosf(ang, &sv, &cv);
      tile[k*EPOS + p]      = (uint16_t)f2bf(sv);
      tile[(64+k)*EPOS + p] = (uint16_t)f2bf(cv);
    }
    if (tid < 128){                          // type rows 128..131 x 32 p
      int r = 128 + (tid >> 5), p = tid & (EPOS-1);
      int et = etype[base + p];
      tile[r*EPOS + p] = (uint16_t)f2bf(temb[et*4 + (r-128)]);
    }
    // pad rows 132..143 zero (12 rows x 32)
    for (int e = tid; e < 12*EPOS; e += 256)
      tile[(H_ + (e >> 5))*EPOS + (e & (EPOS-1))] = 0;
    if (tid < EPOS){
      int bl = base + tid;
      int et = etype[bl];
      float t0 = temb[et*4+0], t1 = temb[et*4+1], t2 = temb[et*4+2], t3 = temb[et*4+3];
      sc4[bl]          = t0*Wg[0]+t1*Wg[1]+t2*Wg[2]+t3*Wg[3];  // dg  (j-side)
      sc4[NP_ + bl]    = t0*Wg[4]+t1*Wg[5]+t2*Wg[6]+t3*Wg[7];  // dg2 (i-side)
      sc4[2*NP_ + bl]  = t0*Wl[0]+t1*Wl[1]+t2*Wl[2]+t3*Wl[3];  // dl
      sc4[3*NP_ + bl]  = t0*Wl[4]+t1*Wl[5]+t2*Wl[6]+t3*Wl[7];  // dl2
      outmean[bl] = 0.f;                                        // zero for k4 atomics
    }
    __syncthreads();
    // writeout: 144 rows x 64B = 576 x 16B chunks
    for (int e = tid; e < HPAD*4; e += 256){
      int r = e >> 2, c = e & 3;
      ((uint4v*)(hvT + ((size_t)b*HPAD + r)*L_ + l0))[c] = ((const uint4v*)(tile + r*EPOS))[c];
    }
  } else {
    int pb = blk - EBLK;               // 0..18
    if (pb < 9){                       // W_noise bf16 image + rowsum(bf16 W)
      for (int e = tid; e < 16*KSTR; e += 256){
        int r = e / KSTR, k = e - r*KSTR;
        int n = pb*16 + r;
        uint16_t v = 0;
        if (n < H_ && k < H_) v = (uint16_t)f2bf(Wn[n*H_ + k]);
        wbf[n*KSTR + k] = v;
      }
      if (tid < 16){
        int n = pb*16 + tid;
        if (n < H_){
          float s = 0.f;
          const float* row = Wn + (size_t)n*H_;
          #pragma unroll 4
          for (int k = 0; k < H_; ++k) s += bf_round(row[k]);
          rs[n] = s;
        }
      }
    } else {                           // [Win; Wpred] bf16 image
      int rb = pb - 9;                 // 0..9
      for (int e = tid; e < 16*KSTR; e += 256){
        int r = e / KSTR, k = e - r*KSTR;
        int n = rb*16 + r;
        uint16_t v = 0;
        if (k < H_){
          if (n < H_)          v = (uint16_t)f2bf(Win[n*H_ + k]);
          else if (n < H_+NT_) v = (uint16_t)f2bf(Wpred[(n-H_)*H_ + k]);
        }
        wd[n*KSTR + k] = v;
      }
    }
  }
}

// ---------------- K1: attention flash-tile + LN + fused decoder --------------------
// R25: revert to the R9-proven 256-thread version (R11's 512-thread variant
// regressed ~7us: worse block packing + 2x in-block tile imbalance at stride 8).
// R22: transposed grid (id = b + 32*i_tile) for per-CU load balance; sc4 SoA.
// R20: causal truncation (KTM4 k-tiles). Decoder writes cvec - rs.
__global__ __launch_bounds__(256) void k1_attn(
    const float* __restrict__ etime, const float* __restrict__ sc4,
    const uint16_t* __restrict__ hvT, const uint16_t* __restrict__ wd,
    const float* __restrict__ bgp, const float* __restrict__ blp,
    const float* __restrict__ gamma, const float* __restrict__ beta,
    const float* __restrict__ rs,
    float* __restrict__ cvec, float* __restrict__ outp){
  __shared__ __align__(16) uint16_t scb[ITILE*SCSTR];
  __shared__ float jt[L_], jg[L_], jl[L_];
  __shared__ float rt[ITILE], rg[ITILE], rl[ITILE];
  __shared__ __align__(16) float hid[ITILE*HIDS];
  __shared__ __align__(16) uint16_t hnl[ITILE*HNLS];
  __shared__ float logit[ITILE*NT_];
  __shared__ float mur[ITILE], rsr[ITILE];
  int b = blockIdx.x, i0 = blockIdx.y*ITILE, base = b*L_;   // transposed grid
  int tid = threadIdx.x;
  float bg = bgp[0], blv = blp[0];
  int KTM4 = (((i0 + 14) >> 5) + 4) & ~3;   // 4..16 k-tiles actually needed (rounded to 4)
  int JMAX4 = KTM4 << 5;                    // 128..512
  for (int j = tid; j < L_; j += 256){
    jt[j] = etime[base+j];
    jg[j] = sc4[base+j];            // dg plane (SoA, coalesced)
    jl[j] = sc4[2*NP_ + base+j];    // dl plane
  }
  if (tid < ITILE){
    rt[tid] = etime[base+i0+tid];
    rg[tid] = sc4[NP_   + base+i0+tid];   // dg2
    rl[tid] = sc4[3*NP_ + base+i0+tid];   // dl2
  }
  __syncthreads();
  // phase 1: score tile, truncated at JMAX4 (j >= JMAX4 never read by MFMA)
  for (int e = tid; e < ITILE*L_; e += 256){
    int r = e >> 9, j = e & (L_-1);
    if (j >= JMAX4) continue;                 // wave-uniform skip
    float v = 0.f;
    if (j < i0 + r){
      float gate = __frcp_rn(1.f + __expf(-(jg[j] + rg[r] + bg)));
      float ls   = softplus_fast(jl[j] + rl[r] + blv) + 1e-6f;
      float d    = rt[r] - jt[j];
      float t2   = 2.f*ls*ls;
      v = gate * t2 * __frcp_rn(t2 + d*d);
    }
    scb[r*SCSTR + j] = (uint16_t)f2bf(v);
  }
  __syncthreads();
  // phase 2: hidden[16][H] = scores @ hv  (MFMA 16x16x32, B from hvT short8)
  int wave = tid>>6, lane = tid&63, q = lane>>4, col = lane&15;
  for (int nt = wave; nt < NTIL; nt += 4){
    int n = nt*16 + col;
    const uint16_t* bT = hvT + ((size_t)b*HPAD + n)*L_;   // 144 rows, pad rows zero
    float4v acc = {0.f,0.f,0.f,0.f};
    if (KTM4 == 16){
      // heavy blocks: R13 path -- all 16 independent B-loads in flight
      short8 bfr[16];
      #pragma unroll
      for (int kt = 0; kt < 16; ++kt)
        bfr[kt] = *(const short8*)&bT[kt*32 + q*8];
      #pragma unroll
      for (int kt = 0; kt < 16; ++kt){
        short8 af = *(const short8*)&scb[col*SCSTR + kt*32 + q*8];
        acc = __builtin_amdgcn_mfma_f32_16x16x32_bf16(af, bfr[kt], acc, 0, 0, 0);
      }
    } else {
      for (int ktc = 0; ktc < KTM4; ktc += 4){
        const uint16_t* bc = bT + ktc*32 + q*8;
        short8 b0 = *(const short8*)&bc[0];
        short8 b1 = *(const short8*)&bc[32];
        short8 b2 = *(const short8*)&bc[64];
        short8 b3 = *(const short8*)&bc[96];
        const uint16_t* ac = scb + col*SCSTR + ktc*32 + q*8;
        acc = __builtin_amdgcn_mfma_f32_16x16x32_bf16(*(const short8*)&ac[0],  b0, acc, 0, 0, 0);
        acc = __builtin_amdgcn_mfma_f32_16x16x32_bf16(*(const short8*)&ac[32], b1, acc, 0, 0, 0);
        acc = __builtin_amdgcn_mfma_f32_16x16x32_bf16(*(const short8*)&ac[64], b2, acc, 0, 0, 0);
        acc = __builtin_amdgcn_mfma_f32_16x16x32_bf16(*(const short8*)&ac[96], b3, acc, 0, 0, 0);
      }
    }
    if (n < H_){
      #pragma unroll
      for (int rr = 0; rr < 4; ++rr)
        hid[(q*4+rr)*HIDS + n] = acc[rr];    // C/D: row=q*4+rr, col=n
    }
  }
  __syncthreads();
  // LayerNorm stats
  #pragma unroll
  for (int rr = 0; rr < 4; ++rr){
    int r = wave*4 + rr;
    float x0 = hid[r*HIDS + lane];
    float x1 = hid[r*HIDS + 64 + lane];
    float x2 = (lane<4) ? hid[r*HIDS + 128 + lane] : 0.f;
    float s1 = x0+x1+x2, s2 = x0*x0+x1*x1+x2*x2;
    #pragma unroll
    for (int m=32; m; m>>=1){ s1 += __shfl_xor(s1, m, 64); s2 += __shfl_xor(s2, m, 64); }
    if (lane == 0){
      float mu = s1 * (1.f/132.f);
      float var = s2 * (1.f/132.f) - mu*mu;
      mur[r] = mu; rsr[r] = rsqrtf(var + 1e-6f);
    }
  }
  __syncthreads();
  if (tid < HNLS){
    if (tid < H_){
      float g = gamma[tid], be = beta[tid];
      #pragma unroll 4
      for (int r = 0; r < ITILE; ++r)
        hnl[r*HNLS + tid] = (uint16_t)f2bf((hid[r*HIDS+tid]-mur[r])*rsr[r]*g + be);
    } else {
      #pragma unroll 4
      for (int r = 0; r < ITILE; ++r) hnl[r*HNLS + tid] = 0;
    }
  }
  __syncthreads();
  // fused decoder: hn(16x132) @ wd(152x132)^T -> (cvec - rs) + logits
  short8 afr[KCH];
  #pragma unroll
  for (int kc = 0; kc < KCH; ++kc)
    afr[kc] = *(const short8*)&hnl[col*HNLS + kc*32 + q*8];   // A[m=col][k]
  for (int nt = wave; nt < NTIL3; nt += 4){
    float4v acc = {0.f,0.f,0.f,0.f};
    const short8* bp = (const short8*)&wd[(nt*16+col)*KSTR];
    #pragma unroll
    for (int kc = 0; kc < KCH; ++kc){
      // kc=4,q>0 reads past wd row end: A zero at k>=132 -- harmless
      short8 bfr = bp[kc*4 + q];
      acc = __builtin_amdgcn_mfma_f32_16x16x32_bf16(afr[kc], bfr, acc, 0, 0, 0);
    }
    int n = nt*16 + col;
    #pragma unroll
    for (int rr = 0; rr < 4; ++rr){
      int lr = q*4 + rr;
      if (n < H_)            cvec[(size_t)(base+i0+lr)*H_ + n] = acc[rr] - rs[n];
      else if (n < H_+NT_)   logit[lr*NT_ + (n-H_)] = acc[rr];
    }
  }
  __syncthreads();
  if (tid < ITILE){
    float mx = -1e30f;
    #pragma unroll
    for (int j=0;j<NT_;++j) mx = fmaxf(mx, logit[tid*NT_+j]);
    float ex[NT_]; float ssum = 0.f;
    #pragma unroll
    for (int j=0;j<NT_;++j){ ex[j] = __expf(logit[tid*NT_+j]-mx); ssum += ex[j]; }
    float inv = __frcp_rn(ssum);
    #pragma unroll
    for (int j=0;j<NT_;++j)
      outp[(size_t)(B_*L_) + (size_t)(base+i0+tid)*NT_ + j] = ex[j]*inv;
  }
}

// ---------------- K4: GAN sampler (R9-proven config, byte-identical) ---------------
__global__ __launch_bounds__(512, 4) void k4_sampler(
    const uint16_t* __restrict__ wbf, const float* __restrict__ cvec,
    const float* __restrict__ wt, float* __restrict__ outmean){
  __shared__ __align__(16) short Wlds[WBF_N + 32];  // +32: slack for kc=4 tail over-read
  __shared__ float wtlds[HPAD];
  __shared__ float part[128];
  int tid = threadIdx.x, lane = tid & 63;
  int l0 = blockIdx.x*16, b = blockIdx.y, sch = blockIdx.z;
  int bl0 = b*L_ + l0;

  {   // stage W (incl. slack words -- keeps kc=4 over-read finite): 2452 x 16B
    const uint4v* g = (const uint4v*)wbf;
    uint4v* l = (uint4v*)Wlds;
    for (int idx = tid; idx < (WBF_N+32)/8; idx += 512) l[idx] = g[idx];
  }
  if (tid < HPAD) wtlds[tid] = (tid < H_) ? wt[tid] : 0.f;
  if (tid < 128) part[tid] = 0.f;
  __syncthreads();

  int wave = tid >> 6;
  int q = lane >> 4, col = lane & 15;
  int s = sch*8 + wave;
  if (s < SMP_){
    uint32_t fbase = (uint32_t)(bl0 + col)*(uint32_t)(SMP_*H_)
                   + (uint32_t)s*(uint32_t)H_;
    uint32_t fbq = fbase + (uint32_t)(q*8);
    uint4v afu[KCH];
    #pragma unroll
    for (int kc = 0; kc < 4; ++kc){
      #pragma unroll
      for (int t = 0; t < 4; ++t)
        afu[kc][t] = tfpair(fbq + (uint32_t)(kc*32 + 2*t),
                            fbq + (uint32_t)(kc*32 + 2*t + 1));
    }
    {   // tail features 128..131: one full-wave stream (q even:128/129, q odd:130/131)
      uint32_t ft = fbase + 128u + (uint32_t)((q & 1)*2);
      uint32_t w  = tfpair(ft, ft + 1u);
      uint32_t wo = (uint32_t)__shfl_xor((int)w, 16, 64);
      uint4v a4 = {0u,0u,0u,0u};
      if (q == 0){ a4[0] = w; a4[1] = wo; }
      afu[4] = a4;
    }
    const float* cbase = cvec + (size_t)(bl0 + q*4)*H_;
    float racc0=0.f, racc1=0.f, racc2=0.f, racc3=0.f;
    for (int nt = 0; nt < NTIL; ++nt){
      float4v acc = {0.f,0.f,0.f,0.f};
      const short8* bp = (const short8*)&Wlds[(nt*16+col)*KSTR];
      #pragma unroll
      for (int kc = 0; kc < KCH; ++kc){
        short8 bfr = bp[kc*4 + q];
        acc = __builtin_amdgcn_mfma_f32_16x16x32_bf16(
                 __builtin_bit_cast(short8, afu[kc]), bfr, acc, 0, 0, 0);
      }
      int n = nt*16 + col;
      float wv = wtlds[n];
      const float* cb = cbase + n;
      racc0 += fmaxf(acc[0] + cb[0*H_], 0.f)*wv;
      racc1 += fmaxf(acc[1] + cb[1*H_], 0.f)*wv;
      racc2 += fmaxf(acc[2] + cb[2*H_], 0.f)*wv;
      racc3 += fmaxf(acc[3] + cb[3*H_], 0.f)*wv;
    }
    #pragma unroll
    for (int m = 1; m < 16; m <<= 1){
      racc0 += __shfl_xor(racc0, m, 64);
      racc1 += __shfl_xor(racc1, m, 64);
      racc2 += __shfl_xor(racc2, m, 64);
      racc3 += __shfl_xor(racc3, m, 64);
    }
    if (col == 0){
      part[wave*16 + q*4 + 0] = 0.02f * softplus_fast(racc0);
      part[wave*16 + q*4 + 1] = 0.02f * softplus_fast(racc1);
      part[wave*16 + q*4 + 2] = 0.02f * softplus_fast(racc2);
      part[wave*16 + q*4 + 3] = 0.02f * softplus_fast(racc3);
    }
  }
  __syncthreads();
  if (tid < 16){
    float v = 0.f;
    #pragma unroll
    for (int w = 0; w < 8; ++w) v += part[w*16 + tid];
    atomicAdd(&outmean[bl0 + tid], v);
  }
}

// ---------------- launch ----------------
extern "C" void kernel_launch(void* const* d_in, const int* in_sizes, int n_in,
                              void* d_out, int out_size, void* d_ws, size_t ws_size,
                              hipStream_t stream){
  const int*   etype = (const int*)  d_in[0];
  const float* etime = (const float*)d_in[1];
  const float* Wt    = (const float*)d_in[3];
  const float* temb  = (const float*)d_in[4];
  const float* Wg    = (const float*)d_in[5];
  const float* bgp   = (const float*)d_in[6];
  const float* Wl    = (const float*)d_in[7];
  const float* blp   = (const float*)d_in[8];
  const float* gamma = (const float*)d_in[9];
  const float* beta  = (const float*)d_in[10];
  const float* Win   = (const float*)d_in[11];
  const float* Wn    = (const float*)d_in[12];
  const float* wtm   = (const float*)d_in[13];
  const float* Wpred = (const float*)d_in[14];
  float* out = (float*)d_out;

  uint16_t* hvT   = (uint16_t*)d_ws;                        // 32*144*512 shorts
  float*    sc4   = (float*)(hvT + (size_t)B_*HPAD*L_);     // 4 SoA planes x NP_ floats
  float*    cvec  = sc4 + (size_t)NP_*4;                    // 16384*132 floats
  float*    rs    = cvec + (size_t)NP_*H_;                  // 132 (+pad to 256)
  uint16_t* wbf   = (uint16_t*)(rs + 256);                  // WBF_N shorts
  uint16_t* wd    = wbf + (size_t)WBF_N;                    // WDROW*KSTR shorts

  k0_embed  <<<dim3(EBLK+19),  dim3(256), 0, stream>>>(etype, etime, Wt, temb, Wg, Wl,
                                                       Wn, Win, Wpred, hvT, sc4, out, wbf, wd, rs);
  k1_attn   <<<dim3(32,32),    dim3(256), 0, stream>>>(etime, sc4, hvT, wd, bgp, blp,
                                                       gamma, beta, rs, cvec, out);
  k4_sampler<<<dim3(32,32,7),  dim3(512), 0, stream>>>(wbf, cvec, wtm, out);
}